// Round 1
// baseline (1579.781 us; speedup 1.0000x reference)
//
#include <hip/hip_runtime.h>
#include <math.h>

#define B_LEN 1024
#define T_LEN 256

__device__ __forceinline__ float fast_rcp(float x) { return __builtin_amdgcn_rcpf(x); }
__device__ __forceinline__ float fast_tanh(float x) {
    // tanh(x) = 1 - 2/(exp(2x)+1); exp->v_exp_f32, rcp->v_rcp_f32 (~1 ulp)
    float e = __expf(2.0f * x);
    return 1.0f - 2.0f * fast_rcp(e + 1.0f);
}
__device__ __forceinline__ float softplus_f(float x) {
    return (x > 20.0f) ? x : log1pf(expf(x));
}

// One wave (64 lanes) per batch element. Lane layouts:
//   (i8,j8) = (lane>>3, lane&7)  : 8x8 matrix entry per lane (P, chol, P_pred)
//   (h32,p2)= (lane&31, lane>>5) : layer-1 (hidden unit, sigma parity)
//   (sy,m4) = (lane>>2, lane&3)  : y-side (sigma, measurement)
__global__ __launch_bounds__(64)
void ukf_kernel(const float* __restrict__ X0, const float* __restrict__ U,
                const float* __restrict__ Y,  const float* __restrict__ W1,
                const float* __restrict__ B1, const float* __restrict__ W2,
                const float* __restrict__ B2, const float* __restrict__ HM,
                const float* __restrict__ LQ, const float* __restrict__ LR,
                const float* __restrict__ LP0, float* __restrict__ out)
{
    const int b    = blockIdx.x;
    const int lane = threadIdx.x;
    const int i8   = lane >> 3;
    const int j8   = lane & 7;
    const int h32  = lane & 31;
    const int p2   = lane >> 5;
    const int m4   = lane & 3;
    const int sy   = lane >> 2;

    __shared__ __align__(16) float u_sh[T_LEN * 2];    // u[b] staged once
    __shared__ __align__(16) float y_sh[T_LEN * 4];    // y[b] staged once
    __shared__ __align__(16) float pts_sh[17 * 8];     // sigma points
    __shared__ __align__(16) float hid_sh[17 * 32];    // tanh hidden
    __shared__ __align__(16) float pf_sh[17 * 8];      // pts_f, then dx in place
    __shared__ __align__(16) float yp_sh[17 * 4];      // dy
    __shared__ float x_sh[8];
    __shared__ float xp_sh[8];
    __shared__ float ypred_sh[4];
    __shared__ float Sy_sh[16];
    __shared__ float L4_sh[16];
    __shared__ float Pxy_sh[32];
    __shared__ float K_sh[32];
    __shared__ float T1_sh[32];

    // ---- one-time staging ----
    for (int k = lane; k < T_LEN * 2; k += 64) u_sh[k] = U[(size_t)b * (T_LEN * 2) + k];
    for (int k = lane; k < T_LEN * 4; k += 64) y_sh[k] = Y[(size_t)b * (T_LEN * 4) + k];

    float w1r[10];                       // W1 column h32 (10 inputs)
    #pragma unroll
    for (int d = 0; d < 10; ++d) w1r[d] = W1[d * 32 + h32];
    const float b1r = B1[h32];
    float w2r[32];                       // W2 column j8 (32 hidden)
    #pragma unroll
    for (int h = 0; h < 32; ++h) w2r[h] = W2[h * 8 + j8];
    const float b2r = B2[j8];
    float hmr[8];                        // Hm row m4
    #pragma unroll
    for (int d = 0; d < 8; ++d) hmr[d] = HM[m4 * 8 + d];

    const float qdiag = softplus_f(LQ[i8]);
    const float rdiag = softplus_f(LR[m4]);

    const size_t Xbase = (size_t)b * T_LEN * 8;
    const size_t Pbase = (size_t)B_LEN * T_LEN * 8  + (size_t)b * T_LEN * 64;
    const size_t qbase = (size_t)B_LEN * T_LEN * 72 + (size_t)b * T_LEN;
    const size_t rbase = (size_t)B_LEN * T_LEN * 73 + (size_t)b * T_LEN;

    // ---- initial state / t=0 outputs ----
    float P = (i8 == j8) ? softplus_f(LP0[i8]) : 0.0f;  // P[i8][j8] in register
    if (j8 == 0) x_sh[i8] = X0[b * 8 + i8];
    if (lane < 8) out[Xbase + lane] = X0[b * 8 + lane];
    out[Pbase + lane] = P;
    if (lane == 0) { out[qbase] = 0.0f; out[rbase] = 0.0f; }
    __syncthreads();

    for (int t = 1; t < T_LEN; ++t) {
        // ================= Cholesky of A = 8*P + 1e-4 I (in-register, shfl) ====
        float a = 8.0f * P + ((i8 == j8) ? 1e-4f : 0.0f);
        #pragma unroll
        for (int j = 0; j < 8; ++j) {
            float dj   = __shfl(a, j * 9);          // updated A[j][j]
            float sq   = sqrtf(dj);
            float rinv = fast_rcp(sq);
            if (j8 == j) a = (i8 == j) ? sq : a * rinv;   // column j scale
            float ci = __shfl(a, i8 * 8 + j);             // L[i8][j]
            float cj = __shfl(a, j8 * 8 + j);             // L[j8][j]
            if (i8 > j && j8 > j) a -= ci * cj;           // rank-1 update
        }
        const float Lx = (j8 <= i8) ? a : 0.0f;           // lower L, zero upper

        // ================= sigma points -> LDS ================================
        const float xi = x_sh[i8];
        if (j8 == 0) pts_sh[i8] = xi;                     // pts[0]
        pts_sh[(1 + j8) * 8 + i8] = xi + Lx;              // pts[1+j] = x + L[:,j]
        pts_sh[(9 + j8) * 8 + i8] = xi - Lx;
        __syncthreads();

        // ================= layer 1: hidden = tanh([pts;u] W1 + b1) ============
        const float u0 = u_sh[(t - 1) * 2 + 0];
        const float u1 = u_sh[(t - 1) * 2 + 1];
        const float ub = b1r + u0 * w1r[8] + u1 * w1r[9];
        #pragma unroll
        for (int s0 = 0; s0 < 9; ++s0) {
            int s = 2 * s0 + p2;
            if (s < 17) {
                const float4 pa = *(const float4*)&pts_sh[s * 8];
                const float4 pb = *(const float4*)&pts_sh[s * 8 + 4];
                float acc = ub
                    + pa.x * w1r[0] + pa.y * w1r[1] + pa.z * w1r[2] + pa.w * w1r[3]
                    + pb.x * w1r[4] + pb.y * w1r[5] + pb.z * w1r[6] + pb.w * w1r[7];
                hid_sh[s * 32 + h32] = fast_tanh(acc);
            }
        }
        __syncthreads();

        // ================= layer 2: pts_f = pts + hidden W2 + b2 ==============
        float pfv0, pfv1, pfv2 = 0.0f;
        {
            const int s = i8;
            float acc = b2r;
            #pragma unroll
            for (int h = 0; h < 32; h += 4) {
                const float4 hv = *(const float4*)&hid_sh[s * 32 + h];
                acc += hv.x * w2r[h] + hv.y * w2r[h + 1] + hv.z * w2r[h + 2] + hv.w * w2r[h + 3];
            }
            pfv0 = pts_sh[s * 8 + j8] + acc;
            pf_sh[s * 8 + j8] = pfv0;
        }
        {
            const int s = 8 + i8;
            float acc = b2r;
            #pragma unroll
            for (int h = 0; h < 32; h += 4) {
                const float4 hv = *(const float4*)&hid_sh[s * 32 + h];
                acc += hv.x * w2r[h] + hv.y * w2r[h + 1] + hv.z * w2r[h + 2] + hv.w * w2r[h + 3];
            }
            pfv1 = pts_sh[s * 8 + j8] + acc;
            pf_sh[s * 8 + j8] = pfv1;
        }
        if (i8 == 0) {
            const int s = 16;
            float acc = b2r;
            #pragma unroll
            for (int h = 0; h < 32; h += 4) {
                const float4 hv = *(const float4*)&hid_sh[s * 32 + h];
                acc += hv.x * w2r[h] + hv.y * w2r[h + 1] + hv.z * w2r[h + 2] + hv.w * w2r[h + 3];
            }
            pfv2 = pts_sh[s * 8 + j8] + acc;
            pf_sh[s * 8 + j8] = pfv2;
        }
        __syncthreads();

        // ================= x_pred (Wm[0]=0, rest 1/16): butterfly over i8 =====
        float part = ((i8 == 0) ? pfv2 : pfv0) + pfv1;   // s=16 replaces s=0
        part += __shfl_xor(part, 8);
        part += __shfl_xor(part, 16);
        part += __shfl_xor(part, 32);
        const float xp = part * 0.0625f;                  // x_pred[j8] (replicated)
        if (i8 == 0) xp_sh[j8] = xp;

        // ================= y_pts = pts_f Hm^T =================================
        float yv0, yv16 = 0.0f;
        {
            const float4 pa = *(const float4*)&pf_sh[sy * 8];
            const float4 pb = *(const float4*)&pf_sh[sy * 8 + 4];
            yv0 = pa.x * hmr[0] + pa.y * hmr[1] + pa.z * hmr[2] + pa.w * hmr[3]
                + pb.x * hmr[4] + pb.y * hmr[5] + pb.z * hmr[6] + pb.w * hmr[7];
        }
        if (sy == 0) {
            const float4 pa = *(const float4*)&pf_sh[16 * 8];
            const float4 pb = *(const float4*)&pf_sh[16 * 8 + 4];
            yv16 = pa.x * hmr[0] + pa.y * hmr[1] + pa.z * hmr[2] + pa.w * hmr[3]
                 + pb.x * hmr[4] + pb.y * hmr[5] + pb.z * hmr[6] + pb.w * hmr[7];
        }
        // y_pred: butterfly over sy (s=16 replaces s=0)
        float py = (sy == 0) ? yv16 : yv0;
        py += __shfl_xor(py, 4);
        py += __shfl_xor(py, 8);
        py += __shfl_xor(py, 16);
        py += __shfl_xor(py, 32);
        const float ypred = py * 0.0625f;                 // y_pred[m4] (replicated)
        if (lane < 4) ypred_sh[lane] = ypred;

        // dy -> LDS ; dx -> pf_sh in place (wave-ordered after y_pts reads)
        yp_sh[sy * 4 + m4] = yv0 - ypred;
        if (sy == 0) yp_sh[16 * 4 + m4] = yv16 - ypred;
        pf_sh[i8 * 8 + j8]       = pfv0 - xp;
        pf_sh[(8 + i8) * 8 + j8] = pfv1 - xp;
        if (i8 == 0) pf_sh[16 * 8 + j8] = pfv2 - xp;
        __syncthreads();

        // ================= P_pred (all 64 lanes) ==============================
        float pp = 0.0f;
        #pragma unroll
        for (int s = 1; s < 17; ++s)
            pp += pf_sh[s * 8 + i8] * pf_sh[s * 8 + j8];
        pp *= 0.0625f;
        pp += 2.0f * pf_sh[i8] * pf_sh[j8];               // Wc[0] = 2
        const float Ppred = pp + ((i8 == j8) ? (qdiag + 1e-4f) : 0.0f);

        // ================= Sy (lanes 0..15) ===================================
        float syv = 0.0f;
        if (lane < 16) {
            float acc = 0.0f;
            #pragma unroll
            for (int s = 1; s < 17; ++s)
                acc += yp_sh[s * 4 + sy] * yp_sh[s * 4 + m4];
            syv = acc * 0.0625f + 2.0f * yp_sh[sy] * yp_sh[m4]
                + ((sy == m4) ? rdiag : 0.0f);
            Sy_sh[lane] = syv;
        }
        // ================= Pxy (lanes 16..47) =================================
        if (lane >= 16 && lane < 48) {
            const int idx = lane - 16;
            const int ii = idx >> 2, mm = idx & 3;
            float acc = 0.0f;
            #pragma unroll
            for (int s = 1; s < 17; ++s)
                acc += pf_sh[s * 8 + ii] * yp_sh[s * 4 + mm];
            Pxy_sh[idx] = acc * 0.0625f + 2.0f * pf_sh[ii] * yp_sh[mm];
        }
        __syncthreads();

        // ================= chol4(Sy) + r_e (in-register, lanes 0..15) =========
        float l4v = (lane < 16) ? syv : 0.0f;
        float re = 0.0f;
        #pragma unroll
        for (int j = 0; j < 4; ++j) {
            float dj   = __shfl(l4v, j * 5);
            float sq   = sqrtf(dj);
            float rinv = fast_rcp(sq);
            re += __logf(sq);                              // all lanes accumulate
            if (lane < 16 && m4 == j) l4v = (sy == j) ? sq : l4v * rinv;
            float ci = __shfl(l4v, ((sy * 4 + j) & 63));
            float cj = __shfl(l4v, ((m4 * 4 + j) & 63));
            if (lane < 16 && sy > j && m4 > j) l4v -= ci * cj;
        }
        if (lane < 16) L4_sh[lane] = l4v;
        __syncthreads();

        // ================= K = Pxy Sy^{-1}: tri-solves, lanes 0..7 ============
        if (lane < 8) {
            const float p0  = Pxy_sh[lane * 4 + 0];
            const float p1  = Pxy_sh[lane * 4 + 1];
            const float p2v = Pxy_sh[lane * 4 + 2];
            const float p3  = Pxy_sh[lane * 4 + 3];
            const float L00 = L4_sh[0],  L10 = L4_sh[4],  L11 = L4_sh[5];
            const float L20 = L4_sh[8],  L21 = L4_sh[9],  L22 = L4_sh[10];
            const float L30 = L4_sh[12], L31 = L4_sh[13], L32 = L4_sh[14], L33 = L4_sh[15];
            const float r0 = fast_rcp(L00), r1 = fast_rcp(L11);
            const float r2 = fast_rcp(L22), r3 = fast_rcp(L33);
            const float w0 = p0 * r0;
            const float w1 = (p1 - L10 * w0) * r1;
            const float w2 = (p2v - L20 * w0 - L21 * w1) * r2;
            const float w3 = (p3 - L30 * w0 - L31 * w1 - L32 * w2) * r3;
            const float k3 = w3 * r3;
            const float k2 = (w2 - L32 * k3) * r2;
            const float k1 = (w1 - L21 * k2 - L31 * k3) * r1;
            const float k0 = (w0 - L10 * k1 - L20 * k2 - L30 * k3) * r0;
            K_sh[lane * 4 + 0] = k0;
            K_sh[lane * 4 + 1] = k1;
            K_sh[lane * 4 + 2] = k2;
            K_sh[lane * 4 + 3] = k3;
        }
        __syncthreads();

        // ================= T1 = K * Sy (lanes 0..31) ==========================
        if (lane < 32) {
            const int ii = lane >> 2, aa = lane & 3;
            T1_sh[lane] = K_sh[ii * 4 + 0] * Sy_sh[0 + aa]
                        + K_sh[ii * 4 + 1] * Sy_sh[4 + aa]
                        + K_sh[ii * 4 + 2] * Sy_sh[8 + aa]
                        + K_sh[ii * 4 + 3] * Sy_sh[12 + aa];
        }
        __syncthreads();

        // ================= P_new = sym(Ppred - T1 K^T) + 1e-4 I ===============
        float m_ = Ppred - (T1_sh[i8 * 4 + 0] * K_sh[j8 * 4 + 0]
                          + T1_sh[i8 * 4 + 1] * K_sh[j8 * 4 + 1]
                          + T1_sh[i8 * 4 + 2] * K_sh[j8 * 4 + 2]
                          + T1_sh[i8 * 4 + 3] * K_sh[j8 * 4 + 3]);
        float mT = __shfl(m_, j8 * 8 + i8);
        P = 0.5f * (m_ + mT) + ((i8 == j8) ? 1e-4f : 0.0f);
        out[Pbase + (size_t)t * 64 + lane] = P;

        // ================= x_new (lanes 0..7) =================================
        if (lane < 8) {
            const float in0 = y_sh[t * 4 + 0] - ypred_sh[0];
            const float in1 = y_sh[t * 4 + 1] - ypred_sh[1];
            const float in2 = y_sh[t * 4 + 2] - ypred_sh[2];
            const float in3 = y_sh[t * 4 + 3] - ypred_sh[3];
            const float xn = xp_sh[lane]
                + K_sh[lane * 4 + 0] * in0 + K_sh[lane * 4 + 1] * in1
                + K_sh[lane * 4 + 2] * in2 + K_sh[lane * 4 + 3] * in3;
            x_sh[lane] = xn;
            out[Xbase + (size_t)t * 8 + lane] = xn;
        }

        // ================= q_e = 0.5 slogdet(P_pred) via chol =================
        float ap = Ppred;
        float qe = 0.0f;
        #pragma unroll
        for (int j = 0; j < 8; ++j) {
            float dj   = __shfl(ap, j * 9);
            float sq   = sqrtf(dj);
            qe += __logf(sq);                              // sum log diag(L)
            float rinv = fast_rcp(sq);
            if (j8 == j) ap = (i8 == j) ? sq : ap * rinv;
            float ci = __shfl(ap, i8 * 8 + j);
            float cj = __shfl(ap, j8 * 8 + j);
            if (i8 > j && j8 > j) ap -= ci * cj;
        }
        if (lane == 0) {
            out[qbase + t] = qe;
            out[rbase + t] = re;
        }
        __syncthreads();
    }
}

extern "C" void kernel_launch(void* const* d_in, const int* in_sizes, int n_in,
                              void* d_out, int out_size, void* d_ws, size_t ws_size,
                              hipStream_t stream) {
    (void)in_sizes; (void)n_in; (void)out_size; (void)d_ws; (void)ws_size;
    const float* X0 = (const float*)d_in[0];
    const float* U  = (const float*)d_in[1];
    const float* Y  = (const float*)d_in[2];
    const float* W1 = (const float*)d_in[3];
    const float* B1 = (const float*)d_in[4];
    const float* W2 = (const float*)d_in[5];
    const float* B2 = (const float*)d_in[6];
    const float* HM = (const float*)d_in[7];
    const float* LQ = (const float*)d_in[8];
    const float* LR = (const float*)d_in[9];
    const float* LP0 = (const float*)d_in[10];
    float* out = (float*)d_out;
    ukf_kernel<<<dim3(B_LEN), dim3(64), 0, stream>>>(X0, U, Y, W1, B1, W2, B2,
                                                     HM, LQ, LR, LP0, out);
}